// Round 1
// baseline (468.546 us; speedup 1.0000x reference)
//
#include <hip/hip_runtime.h>
#include <math.h>

#define T_TOK 16384
#define D_DIM 4096
#define E_EXP 64

// Output layout in d_out (all float32):
//   logits   [T,64]      @ 0
//   weights  [T,2]       @ 1048576
//   indices  [T,2]       @ 1081344   (float-encoded ints)
//   mask     [64,2,T]    @ 1114112   (0.0/1.0)
#define OFF_W   (T_TOK * E_EXP)
#define OFF_I   (OFF_W + T_TOK * 2)
#define OFF_M   (OFF_I + T_TOK * 2)

// ---------------------------------------------------------------------------
// GEMM: logits = x @ w^T + b.  grid=256 blocks (64 tokens each), 256 threads.
// 4 waves per block, each wave owns a D-quarter (1024). 8x8 register tile.
// ---------------------------------------------------------------------------
__global__ __launch_bounds__(256, 1) void gemm_kernel(
    const float* __restrict__ x, const float* __restrict__ w,
    const float* __restrict__ b, float* __restrict__ logits) {
  __shared__ float lds[16384];  // xs[4][32][64] | ws[4][32][64]; reused as red[4][64][64]

  const int tid  = threadIdx.x;
  const int tok0 = blockIdx.x * 64;
  const int wave = tid >> 6;   // D-quarter 0..3
  const int lane = tid & 63;
  const int a    = lane >> 3;  // token group 0..7
  const int bg   = lane & 7;   // expert group 0..7
  const int srow = lane >> 3;  // staging: base row
  const int sf   = lane & 7;   // staging: float4 within 32-float d-chunk

  float acc[8][8];
#pragma unroll
  for (int i = 0; i < 8; i++)
#pragma unroll
    for (int j = 0; j < 8; j++) acc[i][j] = 0.f;

  float* xs = lds + wave * 2048;         // [32 dd][64 tok]
  float* wsm = lds + 8192 + wave * 2048; // [32 dd][64 exp]

  for (int c = 0; c < 32; c++) {
    const int dbase = wave * 1024 + c * 32;
    __syncthreads();
    // stage: 8 iters, 8 lanes cover one row's 32-float d-chunk (coalesced 128B)
#pragma unroll
    for (int i = 0; i < 8; i++) {
      const int row = i * 8 + srow;
      const float4 xv = *(const float4*)(x + (size_t)(tok0 + row) * D_DIM + dbase + sf * 4);
      xs[(sf * 4 + 0) * 64 + row] = xv.x;
      xs[(sf * 4 + 1) * 64 + row] = xv.y;
      xs[(sf * 4 + 2) * 64 + row] = xv.z;
      xs[(sf * 4 + 3) * 64 + row] = xv.w;
      const float4 wv = *(const float4*)(w + (size_t)row * D_DIM + dbase + sf * 4);
      wsm[(sf * 4 + 0) * 64 + row] = wv.x;
      wsm[(sf * 4 + 1) * 64 + row] = wv.y;
      wsm[(sf * 4 + 2) * 64 + row] = wv.z;
      wsm[(sf * 4 + 3) * 64 + row] = wv.w;
    }
    __syncthreads();
#pragma unroll
    for (int dd = 0; dd < 32; dd++) {
      const float4 xv0 = *(const float4*)(xs + dd * 64 + a * 8);
      const float4 xv1 = *(const float4*)(xs + dd * 64 + a * 8 + 4);
      const float4 wv0 = *(const float4*)(wsm + dd * 64 + bg * 8);
      const float4 wv1 = *(const float4*)(wsm + dd * 64 + bg * 8 + 4);
      const float xr[8] = {xv0.x, xv0.y, xv0.z, xv0.w, xv1.x, xv1.y, xv1.z, xv1.w};
      const float wr[8] = {wv0.x, wv0.y, wv0.z, wv0.w, wv1.x, wv1.y, wv1.z, wv1.w};
#pragma unroll
      for (int i = 0; i < 8; i++)
#pragma unroll
        for (int j = 0; j < 8; j++) acc[i][j] = fmaf(xr[i], wr[j], acc[i][j]);
    }
  }

  // cross-wave reduction: red[wave][tok][exp]
  __syncthreads();
#pragma unroll
  for (int i = 0; i < 8; i++) {
    const int tok = a * 8 + i;
    float* dst = lds + wave * 4096 + tok * 64 + bg * 8;
    *(float4*)(dst)     = make_float4(acc[i][0], acc[i][1], acc[i][2], acc[i][3]);
    *(float4*)(dst + 4) = make_float4(acc[i][4], acc[i][5], acc[i][6], acc[i][7]);
  }
  __syncthreads();
#pragma unroll
  for (int v = 0; v < 4; v++) {
    const int f = v * 1024 + tid * 4;
    const float4 s0 = *(const float4*)(lds + f);
    const float4 s1 = *(const float4*)(lds + 4096 + f);
    const float4 s2 = *(const float4*)(lds + 8192 + f);
    const float4 s3 = *(const float4*)(lds + 12288 + f);
    const int e = f & 63;
    const float4 bb = *(const float4*)(b + e);
    float4 o;
    o.x = s0.x + s1.x + s2.x + s3.x + bb.x;
    o.y = s0.y + s1.y + s2.y + s3.y + bb.y;
    o.z = s0.z + s1.z + s2.z + s3.z + bb.z;
    o.w = s0.w + s1.w + s2.w + s3.w + bb.w;
    *(float4*)(logits + (size_t)(tok0 + (f >> 6)) * E_EXP + e) = o;
  }
}

// ---------------------------------------------------------------------------
// Router: softmax + top-2 + renorm + scatter. 1 thread per token.
// ---------------------------------------------------------------------------
__global__ __launch_bounds__(256) void router_kernel(
    const float* __restrict__ logits, float* __restrict__ out) {
  const int t = blockIdx.x * 256 + threadIdx.x;
  const float* lp = logits + (size_t)t * E_EXP;

  float l[64];
#pragma unroll
  for (int i = 0; i < 64; i += 4) {
    const float4 v = *(const float4*)(lp + i);
    l[i] = v.x; l[i + 1] = v.y; l[i + 2] = v.z; l[i + 3] = v.w;
  }
  float m = l[0];
#pragma unroll
  for (int i = 1; i < 64; i++) m = fmaxf(m, l[i]);
  float e[64];
  float s = 0.f;
#pragma unroll
  for (int i = 0; i < 64; i++) { e[i] = expf(l[i] - m); s += e[i]; }

  // top-2 on e (ordering identical to probs; strict > keeps lowest index on ties)
  float v1 = -1.f, v2 = -1.f;
  int i1 = 0, i2 = 0;
#pragma unroll
  for (int i = 0; i < 64; i++) {
    const float ei = e[i];
    if (ei > v1) { v2 = v1; i2 = i1; v1 = ei; i1 = i; }
    else if (ei > v2) { v2 = ei; i2 = i; }
  }
  const float pr1 = v1 / s, pr2 = v2 / s;
  const float rs = pr1 + pr2;
  out[OFF_W + t * 2 + 0] = pr1 / rs;
  out[OFF_W + t * 2 + 1] = pr2 / rs;
  out[OFF_I + t * 2 + 0] = (float)i1;
  out[OFF_I + t * 2 + 1] = (float)i2;
  // mask[e][k][t]
  out[OFF_M + (size_t)(i1 * 2 + 0) * T_TOK + t] = 1.0f;
  out[OFF_M + (size_t)(i2 * 2 + 1) * T_TOK + t] = 1.0f;
}

extern "C" void kernel_launch(void* const* d_in, const int* in_sizes, int n_in,
                              void* d_out, int out_size, void* d_ws, size_t ws_size,
                              hipStream_t stream) {
  const float* x  = (const float*)d_in[0];
  const float* w  = (const float*)d_in[1];
  const float* b  = (const float*)d_in[2];
  float* out = (float*)d_out;

  // zero the one-hot mask region (re-poisoned to 0xAA before every launch)
  hipMemsetAsync(out + OFF_M, 0, (size_t)E_EXP * 2 * T_TOK * sizeof(float), stream);

  gemm_kernel<<<T_TOK / 64, 256, 0, stream>>>(x, w, b, out);
  router_kernel<<<T_TOK / 256, 256, 0, stream>>>(out, out);
}

// Round 2
// 412.341 us; speedup vs baseline: 1.1363x; 1.1363x over previous
//
#include <hip/hip_runtime.h>
#include <math.h>

#define T_TOK 16384
#define D_DIM 4096
#define E_EXP 64

// d_out layout (float32): logits [T,64] | weights [T,2] | indices [T,2] | mask [64,2,T]
#define OFF_W   (T_TOK * E_EXP)
#define OFF_I   (OFF_W + T_TOK * 2)
#define OFF_M   (OFF_I + T_TOK * 2)

// Per-wave LDS slices (floats). x: [32 dd][32 tok] pad->36, w: [32 dd][64 exp] pad->68.
// Strides chosen so inner-loop ds_read_b128 are 16B-aligned and conflict-free/2-way.
#define XS_STRIDE 36
#define WS_STRIDE 68
#define XS_SIZE   (32 * XS_STRIDE)      // 1152
#define WS_SIZE   (32 * WS_STRIDE)      // 2176
#define WAVE_LDS  (XS_SIZE + WS_SIZE)   // 3328 floats per wave
#define RED_STRIDE 68
#define LG_BASE   (4 * WAVE_LDS)                  // 13312
#define LDS_FLOATS (LG_BASE + 32 * RED_STRIDE)    // 15488 floats = 61952 B -> 2 blocks/CU

__global__ __launch_bounds__(256, 2) void moe_router_kernel(
    const float* __restrict__ x, const float* __restrict__ w,
    const float* __restrict__ b, float* __restrict__ out) {
  __shared__ __align__(16) float lds[LDS_FLOATS];

  const int tid  = threadIdx.x;
  const int wave = tid >> 6;      // owns D-quarter [wave*1024, wave*1024+1024)
  const int lane = tid & 63;
  const int tok0 = blockIdx.x * 32;
  const int q = lane & 7;         // staging: float4 slot within 32-float chunk
  const int r = lane >> 3;        // staging: row group
  const int tg = lane >> 3;       // compute tile: 4 tokens  (tok = tg*4+i)
  const int eg = lane & 7;        // compute tile: 8 experts (exp = eg*8+j)

  float* xs  = lds + wave * WAVE_LDS;
  float* wsb = xs + XS_SIZE;

  float acc[4][8];
#pragma unroll
  for (int i = 0; i < 4; i++)
#pragma unroll
    for (int j = 0; j < 8; j++) acc[i][j] = 0.f;

  const float* xbase = x + (size_t)tok0 * D_DIM + wave * 1024 + q * 4;
  const float* wbase = w + wave * 1024 + q * 4;

  // ---- pipeline helpers -------------------------------------------------
  auto load_chunk = [&](int c, float4* xv, float4* wv) {
    const float* xp = xbase + c * 32;
#pragma unroll
    for (int p = 0; p < 4; p++)
      xv[p] = *(const float4*)(xp + (size_t)(p * 8 + r) * D_DIM);
    const float* wp = wbase + c * 32;
#pragma unroll
    for (int p = 0; p < 8; p++)
      wv[p] = *(const float4*)(wp + (size_t)(p * 8 + r) * D_DIM);
  };
  auto stage_chunk = [&](const float4* xv, const float4* wv) {
#pragma unroll
    for (int p = 0; p < 4; p++) {
      const int row = p * 8 + r;
      xs[(q * 4 + 0) * XS_STRIDE + row] = xv[p].x;
      xs[(q * 4 + 1) * XS_STRIDE + row] = xv[p].y;
      xs[(q * 4 + 2) * XS_STRIDE + row] = xv[p].z;
      xs[(q * 4 + 3) * XS_STRIDE + row] = xv[p].w;
    }
#pragma unroll
    for (int p = 0; p < 8; p++) {
      const int e = p * 8 + r;
      wsb[(q * 4 + 0) * WS_STRIDE + e] = wv[p].x;
      wsb[(q * 4 + 1) * WS_STRIDE + e] = wv[p].y;
      wsb[(q * 4 + 2) * WS_STRIDE + e] = wv[p].z;
      wsb[(q * 4 + 3) * WS_STRIDE + e] = wv[p].w;
    }
  };
  auto compute_chunk = [&]() {
#pragma unroll 8
    for (int dd = 0; dd < 32; dd++) {
      const float4 xr = *(const float4*)(xs + dd * XS_STRIDE + tg * 4);
      const float4 w0 = *(const float4*)(wsb + dd * WS_STRIDE + eg * 8);
      const float4 w1 = *(const float4*)(wsb + dd * WS_STRIDE + eg * 8 + 4);
      const float xa[4] = {xr.x, xr.y, xr.z, xr.w};
      const float wa[8] = {w0.x, w0.y, w0.z, w0.w, w1.x, w1.y, w1.z, w1.w};
#pragma unroll
      for (int i = 0; i < 4; i++)
#pragma unroll
        for (int j = 0; j < 8; j++) acc[i][j] = fmaf(xa[i], wa[j], acc[i][j]);
    }
  };

  // ---- barrier-free K-loop (each wave touches only its own LDS slice) ---
  float4 xv0[4], wv0[8], xv1[4], wv1[8];
  load_chunk(0, xv0, wv0);
#pragma unroll 1
  for (int c = 0; c < 32; c += 2) {
    stage_chunk(xv0, wv0);
    load_chunk(c + 1, xv1, wv1);   // prefetch overlaps compute below
    compute_chunk();
    stage_chunk(xv1, wv1);
    if (c + 2 < 32) load_chunk(c + 2, xv0, wv0);
    compute_chunk();
  }

  // ---- cross-wave reduction: each wave writes partials to its own slice --
  {
    float* red = xs;  // reuse own staging region (2176 <= 3328 floats)
#pragma unroll
    for (int i = 0; i < 4; i++) {
      const int row = tg * 4 + i;
      float* rp = red + row * RED_STRIDE + eg * 8;
      *(float4*)rp       = make_float4(acc[i][0], acc[i][1], acc[i][2], acc[i][3]);
      *(float4*)(rp + 4) = make_float4(acc[i][4], acc[i][5], acc[i][6], acc[i][7]);
    }
  }
  __syncthreads();

  // ---- reduce 4 waves + bias; write logits to global + Lg to LDS --------
  {
    const int tok = tid >> 3;
    const int e8  = (tid & 7) * 8;
    float4 s0 = make_float4(0.f, 0.f, 0.f, 0.f);
    float4 s1 = make_float4(0.f, 0.f, 0.f, 0.f);
#pragma unroll
    for (int wv = 0; wv < 4; wv++) {
      const float* rp = lds + wv * WAVE_LDS + tok * RED_STRIDE + e8;
      const float4 a0 = *(const float4*)rp;
      const float4 a1 = *(const float4*)(rp + 4);
      s0.x += a0.x; s0.y += a0.y; s0.z += a0.z; s0.w += a0.w;
      s1.x += a1.x; s1.y += a1.y; s1.z += a1.z; s1.w += a1.w;
    }
    const float4 b0 = *(const float4*)(b + e8);
    const float4 b1 = *(const float4*)(b + e8 + 4);
    s0.x += b0.x; s0.y += b0.y; s0.z += b0.z; s0.w += b0.w;
    s1.x += b1.x; s1.y += b1.y; s1.z += b1.z; s1.w += b1.w;
    float* lp = out + (size_t)(tok0 + tok) * E_EXP + e8;
    *(float4*)lp       = s0;
    *(float4*)(lp + 4) = s1;
    float* lg = lds + LG_BASE + tok * RED_STRIDE + e8;
    *(float4*)lg       = s0;
    *(float4*)(lg + 4) = s1;
  }
  __syncthreads();

  // ---- fused router: top-2 on raw logits, renormalized weights ----------
  if (tid < 32) {
    const int tok = tid;
    const float* lg = lds + LG_BASE + tok * RED_STRIDE;
    float v1 = -1e30f, v2 = -1e30f;
    int i1 = 0, i2 = 0;
    for (int e = 0; e < 64; e++) {
      const float le = lg[e];
      if (le > v1)      { v2 = v1; i2 = i1; v1 = le; i1 = e; }
      else if (le > v2) { v2 = le; i2 = e; }
    }
    // renormalized top-2 softmax weights: w1 = 1/(1+exp(l2-l1)), w2 = exp(l2-l1)*w1
    const float d  = expf(v2 - v1);
    const float w1 = 1.f / (1.f + d);
    const float w2 = d * w1;
    const int t = tok0 + tok;
    out[OFF_W + t * 2 + 0] = w1;
    out[OFF_W + t * 2 + 1] = w2;
    out[OFF_I + t * 2 + 0] = (float)i1;
    out[OFF_I + t * 2 + 1] = (float)i2;
    out[OFF_M + (size_t)(i1 * 2 + 0) * T_TOK + t] = 1.0f;
    out[OFF_M + (size_t)(i2 * 2 + 1) * T_TOK + t] = 1.0f;
  }
}

extern "C" void kernel_launch(void* const* d_in, const int* in_sizes, int n_in,
                              void* d_out, int out_size, void* d_ws, size_t ws_size,
                              hipStream_t stream) {
  const float* x = (const float*)d_in[0];
  const float* w = (const float*)d_in[1];
  const float* b = (const float*)d_in[2];
  float* out = (float*)d_out;

  // zero the one-hot mask region (re-poisoned to 0xAA before every launch)
  hipMemsetAsync(out + OFF_M, 0, (size_t)E_EXP * 2 * T_TOK * sizeof(float), stream);

  moe_router_kernel<<<T_TOK / 32, 256, 0, stream>>>(x, w, b, out);
}